// Round 6
// baseline (616.705 us; speedup 1.0000x reference)
//
#include <hip/hip_runtime.h>
#include <math.h>

// Problem constants
#define TT 16384   // B*N tokens
#define HH 1024    // hidden
#define DD 2048    // expert inner dim
#define EE 8       // experts
#define MAXTILES 160  // >= EE + TT/128

typedef float f32x4 __attribute__((ext_vector_type(4)));
typedef __bf16 bf16x8 __attribute__((ext_vector_type(8)));

__device__ __forceinline__ unsigned short f2bf(float f) {
  union { float f; unsigned u; } v; v.f = f;
  unsigned r = v.u + 0x7FFFu + ((v.u >> 16) & 1u);  // RNE
  return (unsigned short)(r >> 16);
}

// async global->LDS 16B per lane; LDS dest = wave-uniform base + lane*16
__device__ __forceinline__ void gl2lds16(const unsigned short* g, unsigned short* l) {
  __builtin_amdgcn_global_load_lds(
      (const __attribute__((address_space(1))) void*)g,
      (__attribute__((address_space(3))) void*)l, 16, 0, 0);
}

// ---------------- merged transpose+convert (both weights) + accumulator init ----------------
// [E][R][C] fp32 -> [E][C][R] bf16, 64x64 tiles. Block 0 additionally zeroes the
// router accumulators + ticket (replaces k_init; runs strictly before k_router).
__global__ __launch_bounds__(256) void k_transpose2(const float* __restrict__ W1s,
                                                    unsigned short* __restrict__ W1d,
                                                    const float* __restrict__ W2s,
                                                    unsigned short* __restrict__ W2d,
                                                    int* counts, float* probs_sum,
                                                    float* ent_sum, int* ticket) {
  if (blockIdx.x == 0) {
    int t0 = threadIdx.x;
    if (t0 < EE) { counts[t0] = 0; probs_sum[t0] = 0.f; }
    if (t0 == 0) { *ent_sum = 0.f; *ticket = 0; }
  }
  const int T1 = EE * (HH / 64) * (DD / 64);   // 4096 tiles for W1
  int bid = blockIdx.x;
  const float* src; unsigned short* dst; int R, C;
  if (bid < T1) { src = W1s; dst = W1d; R = HH; C = DD; }
  else          { bid -= T1; src = W2s; dst = W2d; R = DD; C = HH; }
  int tilesC = C >> 6, tilesR = R >> 6;
  int e = bid / (tilesR * tilesC);
  int rem = bid % (tilesR * tilesC);
  int tr = rem / tilesC, tc = rem % tilesC;
  const float* s = src + (size_t)e * R * C + (size_t)(tr * 64) * C + tc * 64;
  unsigned short* d = dst + (size_t)e * R * C + (size_t)(tc * 64) * R + tr * 64;

  __shared__ float t2[64][65];   // t2[c][r] = s[r][c]
  int t = threadIdx.x;
  int col = t & 63, rbase = t >> 6;
#pragma unroll
  for (int i = 0; i < 16; ++i) {
    int row = rbase + i * 4;
    t2[col][row] = s[(size_t)row * C + col];
  }
  __syncthreads();
#pragma unroll
  for (int i = 0; i < 4; ++i) {
    int p = t + i * 256;
    int rr = p >> 4, ch = (p & 15) << 2;
    ushort4 o;
    o.x = f2bf(t2[rr][ch + 0]);
    o.y = f2bf(t2[rr][ch + 1]);
    o.z = f2bf(t2[rr][ch + 2]);
    o.w = f2bf(t2[rr][ch + 3]);
    *(ushort4*)&d[(size_t)rr * R + ch] = o;
  }
}

// ---------------- router: fp64 logits+argmax, fp32 softmax/entropy, fused x->bf16,
// + inline scan in the LAST block (ticket; replaces k_scan launch) ----------------
__global__ __launch_bounds__(256) void k_router(const float* __restrict__ x,
                                                const float* __restrict__ Wr,
                                                const float* __restrict__ br,
                                                int* __restrict__ eidx,
                                                float* __restrict__ probs_sum,
                                                float* __restrict__ ent_sum,
                                                int* __restrict__ counts,
                                                unsigned short* __restrict__ xb,
                                                int* __restrict__ ticket,
                                                int* __restrict__ offsets,
                                                int* __restrict__ cursor,
                                                int* __restrict__ tileE,
                                                int* __restrict__ tileR0,
                                                int* __restrict__ tileEnd,
                                                int* __restrict__ nTiles,
                                                float* __restrict__ out_scalars) {
  __shared__ float s_p[EE];
  __shared__ int   s_c[EE];
  __shared__ float s_e;
  __shared__ int   s_last;
  int tid = threadIdx.x;
  if (tid < EE) { s_p[tid] = 0.f; s_c[tid] = 0; }
  if (tid == 0) s_e = 0.f;
  __syncthreads();
  int lane = tid & 63, w = tid >> 6;
  for (int tt = 0; tt < 4; ++tt) {
    int token = blockIdx.x * 16 + w * 4 + tt;
    double acc[EE];
#pragma unroll
    for (int e = 0; e < EE; ++e) acc[e] = 0.0;
    const float* xr = x + (size_t)token * HH;
    unsigned short* xo = xb + (size_t)token * HH;
#pragma unroll
    for (int i = 0; i < 4; ++i) {
      int hh = i * 256 + lane * 4;
      f32x4 xf = *(const f32x4*)&xr[hh];
      ushort4 o;
      o.x = f2bf(xf[0]); o.y = f2bf(xf[1]); o.z = f2bf(xf[2]); o.w = f2bf(xf[3]);
      *(ushort4*)&xo[hh] = o;               // fused fp32->bf16 conversion
#pragma unroll
      for (int k = 0; k < 4; ++k) {
        double xv = (double)xf[k];
        const float* wr = Wr + (size_t)(hh + k) * EE;
#pragma unroll
        for (int e = 0; e < EE; ++e) acc[e] += xv * (double)wr[e];
      }
    }
#pragma unroll
    for (int off = 32; off > 0; off >>= 1) {
#pragma unroll
      for (int e = 0; e < EE; ++e) acc[e] += __shfl_down(acc[e], off);
    }
    if (lane == 0) {
      double l[EE];
#pragma unroll
      for (int e = 0; e < EE; ++e) l[e] = acc[e] + (double)br[e];
      double m = l[0]; int am = 0;
#pragma unroll
      for (int e = 1; e < EE; ++e) { if (l[e] > m) { m = l[e]; am = e; } }  // first-max semantics
      float p[EE]; float s = 0.f;
#pragma unroll
      for (int e = 0; e < EE; ++e) { p[e] = __expf((float)(l[e] - m)); s += p[e]; }
      float inv = 1.0f / s; float ent = 0.f;
#pragma unroll
      for (int e = 0; e < EE; ++e) { p[e] *= inv; ent -= p[e] * __logf(p[e] + 1e-8f); }
      eidx[token] = am;
#pragma unroll
      for (int e = 0; e < EE; ++e) atomicAdd(&s_p[e], p[e]);
      atomicAdd(&s_e, ent);
      atomicAdd(&s_c[am], 1);
    }
  }
  __syncthreads();
  if (tid < EE) { atomicAdd(&probs_sum[tid], s_p[tid]); atomicAdd(&counts[tid], s_c[tid]); }
  if (tid == 0) atomicAdd(ent_sum, s_e);
  // ---- last block performs the scan (device-scope ticket; all adds fenced before RMW) ----
  if (tid == 0) {
    __threadfence();
    int done = atomicAdd(ticket, 1);
    s_last = (done == (int)gridDim.x - 1) ? 1 : 0;
  }
  __syncthreads();
  if (s_last) {
    __shared__ int soff[EE + 1];
    __shared__ int tbase[EE + 1];
    __shared__ int scnt[EE];
    if (tid == 0) {
      int off = 0, tb = 0; float bal = 0.f;
      for (int e = 0; e < EE; ++e) {
        int c = atomicAdd(&counts[e], 0);          // coherent read (device-scope RMW)
        float ps = atomicAdd(&probs_sum[e], 0.f);
        scnt[e] = c; soff[e] = off; offsets[e] = off; cursor[e] = off;
        tbase[e] = tb;
        tb += (c + 127) >> 7;
        off += c;
        float pi = ps / (float)TT; bal += pi * pi;
        out_scalars[2 + e] = (float)c;             // tokens_per_expert
      }
      soff[EE] = off; offsets[EE] = off; tbase[EE] = tb;
      *nTiles = tb;
      out_scalars[0] = (float)EE * bal;                        // balance_loss
      out_scalars[1] = atomicAdd(ent_sum, 0.f) / (float)TT;    // entropy_loss
    }
    __syncthreads();
    int nt = tbase[EE];
    for (int i = tid; i < nt; i += 256) {
      int e = 0;
      while (tbase[e + 1] <= i) ++e;
      int j = i - tbase[e];
      tileE[i] = e; tileR0[i] = soff[e] + j * 128; tileEnd[i] = soff[e] + scnt[e];
    }
  }
}

// ---------------- build permutation (expert-grouped token order) ----------------
__global__ __launch_bounds__(256) void k_perm(const int* __restrict__ eidx,
                                              int* cursor, int* __restrict__ perm) {
  int t = blockIdx.x * 256 + threadIdx.x;
  int lane = threadIdx.x & 63;
  int mye = eidx[t];
  int pos = 0;
#pragma unroll
  for (int e = 0; e < EE; ++e) {
    unsigned long long mask = __ballot(mye == e);
    if (mask == 0ull) continue;
    int leader = __ffsll(mask) - 1;
    int base = 0;
    if (lane == leader) base = atomicAdd(&cursor[e], __popcll(mask));
    base = __shfl(base, leader);
    if (mye == e) pos = base + (int)__popcll(mask & ((1ull << lane) - 1ull));
  }
  perm[pos] = t;
}

// ================= 128x128-tile BK=64 MFMA GEMMs (round-0 skeleton, half the drains) =================
// Per K-step(64): stage A(128x64)+B(128x64) via 8 global_load_lds/wave, barrier,
// 2 x {8 ds_read_b128 frags, 16 MFMA 16x16x32}, barrier.  Same latency exposure
// per iteration as BK=32 but 2x MFMA work -> half the barrier-drain events.
// LDS rows are 128B: XOR swizzle required (32-way conflict otherwise, G4).
// Physical 16B-slot p at row r holds logical slot p ^ (r&7); staged via
// inverse-swizzled per-lane GLOBAL source (gl2lds LDS dest stays linear),
// read at phys = logical ^ (l16&7).  Read banks: group 4*(slot^(l16&7)) ->
// 8 groups x 8 lanes = conflict-free (optimal 8cy/KB).

// GEMM1: h = gelu(gather_perm(xb) @ Wt1[e] + b1[e]) -> bf16 hbuf (permuted rows)
__global__ __launch_bounds__(256) void k_gemm1(const unsigned short* __restrict__ xb,
                                               const unsigned short* __restrict__ Wt1,
                                               const float* __restrict__ b1,
                                               const int* __restrict__ perm,
                                               const int* __restrict__ tileE,
                                               const int* __restrict__ tileR0,
                                               const int* __restrict__ tileEnd,
                                               const int* __restrict__ nTiles,
                                               unsigned short* __restrict__ hbuf) {
  int tile = blockIdx.y;
  if (tile >= *nTiles) return;
  int e = tileE[tile], r0 = tileR0[tile], rend = tileEnd[tile];
  int c0 = blockIdx.x * 128;
  __shared__ __align__(16) unsigned short As[128 * 64];
  __shared__ __align__(16) unsigned short Bs[128 * 64];
  int tid = threadIdx.x, lane = tid & 63, w = tid >> 6;
  int wr = w >> 1, wc = w & 1;
  int quad = lane >> 4, l16 = lane & 15;
  // staging: instr i covers rows [w*32+i*8, +8); lane -> (row+=lane>>3, phys slot lane&7)
  int lrow = lane >> 3, lslot = lane & 7;
  int sslot = lslot ^ lrow;                       // inverse-swizzled source slot
  const unsigned short* aP[4];
  const unsigned short* bP[4];
  unsigned short* aL[4];
  unsigned short* bL[4];
  const unsigned short* bBase = Wt1 + (size_t)e * ((size_t)DD * HH);
#pragma unroll
  for (int i = 0; i < 4; ++i) {
    int ar = w * 32 + i * 8 + lrow;
    int g = r0 + ar; if (g >= rend) g = rend - 1;
    aP[i] = xb + (size_t)perm[g] * HH + sslot * 8;
    bP[i] = bBase + (size_t)(c0 + ar) * HH + sslot * 8;
    aL[i] = &As[(w * 32 + i * 8) * 64];
    bL[i] = &Bs[(w * 32 + i * 8) * 64];
  }
  f32x4 acc[4][4] = {};
  for (int k0 = 0; k0 < HH; k0 += 64) {
#pragma unroll
    for (int i = 0; i < 4; ++i) { gl2lds16(aP[i] + k0, aL[i]); gl2lds16(bP[i] + k0, bL[i]); }
    __syncthreads();   // compiler drains vmcnt(0) before s_barrier
#pragma unroll
    for (int h = 0; h < 2; ++h) {
      bf16x8 a[4], b[4];
#pragma unroll
      for (int i = 0; i < 4; ++i)
        a[i] = *(const bf16x8*)&As[(wr * 64 + i * 16 + l16) * 64 + (((h << 2) | quad) ^ (l16 & 7)) * 8];
#pragma unroll
      for (int j = 0; j < 4; ++j)
        b[j] = *(const bf16x8*)&Bs[(wc * 64 + j * 16 + l16) * 64 + (((h << 2) | quad) ^ (l16 & 7)) * 8];
#pragma unroll
      for (int i = 0; i < 4; ++i)
#pragma unroll
        for (int j = 0; j < 4; ++j)
          acc[i][j] = __builtin_amdgcn_mfma_f32_16x16x32_bf16(a[i], b[j], acc[i][j], 0, 0, 0);
    }
    __syncthreads();
  }
  float bias[4];
#pragma unroll
  for (int j = 0; j < 4; ++j) bias[j] = b1[e * DD + c0 + wc * 64 + j * 16 + l16];
#pragma unroll
  for (int i = 0; i < 4; ++i) {
#pragma unroll
    for (int r = 0; r < 4; ++r) {
      int gr = r0 + wr * 64 + i * 16 + quad * 4 + r;
      if (gr < rend) {
#pragma unroll
        for (int j = 0; j < 4; ++j) {
          int col = c0 + wc * 64 + j * 16 + l16;
          float v = acc[i][j][r] + bias[j];
          v = 0.5f * v * (1.0f + erff(v * 0.70710678118654752f));  // exact erf GELU
          hbuf[(size_t)gr * DD + col] = f2bf(v);
        }
      }
    }
  }
}

// GEMM2: out[perm[row]] = x + h @ Wt2[e] + b2[e]  (A rows contiguous in hbuf)
__global__ __launch_bounds__(256) void k_gemm2(const unsigned short* __restrict__ hbuf,
                                               const unsigned short* __restrict__ Wt2,
                                               const float* __restrict__ b2,
                                               const float* __restrict__ x,
                                               const int* __restrict__ perm,
                                               const int* __restrict__ tileE,
                                               const int* __restrict__ tileR0,
                                               const int* __restrict__ tileEnd,
                                               const int* __restrict__ nTiles,
                                               float* __restrict__ outp) {
  int tile = blockIdx.y;
  if (tile >= *nTiles) return;
  int e = tileE[tile], r0 = tileR0[tile], rend = tileEnd[tile];
  int c0 = blockIdx.x * 128;
  __shared__ __align__(16) unsigned short As[128 * 64];
  __shared__ __align__(16) unsigned short Bs[128 * 64];
  int tid = threadIdx.x, lane = tid & 63, w = tid >> 6;
  int wr = w >> 1, wc = w & 1;
  int quad = lane >> 4, l16 = lane & 15;
  int lrow = lane >> 3, lslot = lane & 7;
  int sslot = lslot ^ lrow;
  const unsigned short* aP[4];
  const unsigned short* bP[4];
  unsigned short* aL[4];
  unsigned short* bL[4];
  const unsigned short* bBase = Wt2 + (size_t)e * ((size_t)HH * DD);
#pragma unroll
  for (int i = 0; i < 4; ++i) {
    int ar = w * 32 + i * 8 + lrow;
    int g = r0 + ar; if (g >= rend) g = rend - 1;
    aP[i] = hbuf + (size_t)g * DD + sslot * 8;
    bP[i] = bBase + (size_t)(c0 + ar) * DD + sslot * 8;
    aL[i] = &As[(w * 32 + i * 8) * 64];
    bL[i] = &Bs[(w * 32 + i * 8) * 64];
  }
  f32x4 acc[4][4] = {};
  for (int k0 = 0; k0 < DD; k0 += 64) {
#pragma unroll
    for (int i = 0; i < 4; ++i) { gl2lds16(aP[i] + k0, aL[i]); gl2lds16(bP[i] + k0, bL[i]); }
    __syncthreads();
#pragma unroll
    for (int h = 0; h < 2; ++h) {
      bf16x8 a[4], b[4];
#pragma unroll
      for (int i = 0; i < 4; ++i)
        a[i] = *(const bf16x8*)&As[(wr * 64 + i * 16 + l16) * 64 + (((h << 2) | quad) ^ (l16 & 7)) * 8];
#pragma unroll
      for (int j = 0; j < 4; ++j)
        b[j] = *(const bf16x8*)&Bs[(wc * 64 + j * 16 + l16) * 64 + (((h << 2) | quad) ^ (l16 & 7)) * 8];
#pragma unroll
      for (int i = 0; i < 4; ++i)
#pragma unroll
        for (int j = 0; j < 4; ++j)
          acc[i][j] = __builtin_amdgcn_mfma_f32_16x16x32_bf16(a[i], b[j], acc[i][j], 0, 0, 0);
    }
    __syncthreads();
  }
  float bias[4];
#pragma unroll
  for (int j = 0; j < 4; ++j) bias[j] = b2[e * HH + c0 + wc * 64 + j * 16 + l16];
#pragma unroll
  for (int i = 0; i < 4; ++i) {
#pragma unroll
    for (int r = 0; r < 4; ++r) {
      int gr = r0 + wr * 64 + i * 16 + quad * 4 + r;
      if (gr < rend) {
        int tok = perm[gr];
#pragma unroll
        for (int j = 0; j < 4; ++j) {
          int col = c0 + wc * 64 + j * 16 + l16;
          size_t oi = (size_t)tok * HH + col;
          outp[oi] = x[oi] + bias[j] + acc[i][j][r];
        }
      }
    }
  }
}

extern "C" void kernel_launch(void* const* d_in, const int* in_sizes, int n_in,
                              void* d_out, int out_size, void* d_ws, size_t ws_size,
                              hipStream_t stream) {
  const float* x  = (const float*)d_in[0];
  const float* Wr = (const float*)d_in[1];
  const float* br = (const float*)d_in[2];
  const float* W1 = (const float*)d_in[3];
  const float* b1 = (const float*)d_in[4];
  const float* W2 = (const float*)d_in[5];
  const float* b2 = (const float*)d_in[6];
  float* outp = (float*)d_out;

  char* ws = (char*)d_ws;
  int*   counts    = (int*)(ws + 0);
  int*   cursor    = (int*)(ws + 64);
  int*   nTiles    = (int*)(ws + 128);
  float* probs_sum = (float*)(ws + 192);
  float* ent_sum   = (float*)(ws + 256);
  int*   offsets   = (int*)(ws + 320);
  int*   ticket    = (int*)(ws + 448);
  int*   tileE     = (int*)(ws + 512);
  int*   tileR0    = (int*)(ws + 2048);
  int*   tileEnd   = (int*)(ws + 3584);
  int*   eidx      = (int*)(ws + 8192);
  int*   perm      = (int*)(ws + 8192 + 4 * (size_t)TT);
  size_t off = 8192 + 8 * (size_t)TT;
  unsigned short* xb   = (unsigned short*)(ws + off); off += (size_t)TT * HH * 2;        // 32 MB
  unsigned short* Wt1  = (unsigned short*)(ws + off); off += (size_t)EE * DD * HH * 2;   // 32 MB
  unsigned short* Wt2  = (unsigned short*)(ws + off); off += (size_t)EE * HH * DD * 2;   // 32 MB
  unsigned short* hbuf = (unsigned short*)(ws + off); off += (size_t)TT * DD * 2;        // 64 MB

  float* out_scalars = outp + (size_t)TT * HH;

  k_transpose2<<<2 * EE * (HH / 64) * (DD / 64), 256, 0, stream>>>(
      W1, Wt1, W2, Wt2, counts, probs_sum, ent_sum, ticket);
  k_router<<<TT / 16, 256, 0, stream>>>(x, Wr, br, eidx, probs_sum, ent_sum, counts, xb,
                                        ticket, offsets, cursor, tileE, tileR0, tileEnd,
                                        nTiles, out_scalars);
  k_perm<<<TT / 256, 256, 0, stream>>>(eidx, cursor, perm);
  dim3 g1(DD / 128, MAXTILES);
  k_gemm1<<<g1, 256, 0, stream>>>(xb, Wt1, b1, perm, tileE, tileR0, tileEnd, nTiles, hbuf);
  dim3 g2(HH / 128, MAXTILES);
  k_gemm2<<<g2, 256, 0, stream>>>(hbuf, Wt2, b2, x, perm, tileE, tileR0, tileEnd, nTiles, outp);
}